// Round 3
// baseline (123.483 us; speedup 1.0000x reference)
//
#include <hip/hip_runtime.h>

typedef unsigned int u32;

// ---- problem ----
// x:[4,16,8,64,64] f32, w_q/w_k/w_v:[64,8] f32, w_p:[2] f32
// out:[4,16,64,64,64] f32   (World-A: f32 in AND out; bf16 label = threshold mode)
// Attention batch B = bb*64 + t (raw-reinterpret trick):
//   q-side: channel i (all 16), conv row t
//   k/v-side: channel t>>2 (fixed), conv rows (t&3)*16 + j, j in [0,16)
//   uk gets +2*pe; scaling 0.125; residual = mean over m of x[bb, i].

// One thread = one (bb, o, 2x2-patch). Block-uniform (bb, o); weights in LDS.
__global__ __launch_bounds__(256, 1) void adapt_attn(
    const float* __restrict__ x,  const float* __restrict__ wq,
    const float* __restrict__ wk, const float* __restrict__ wv,
    const float* __restrict__ wp, float* __restrict__ out)
{
    __shared__ float s_wk[128];   // w_k rows (o&3)*16 .. +16, laid out [16][8]
    __shared__ float s_wv[128];
    __shared__ float s_wq[8];     // w_q row o

    const int tid = threadIdx.x;
    const int bid = blockIdx.x;           // 1024 blocks = 4 bb * 64 o * 4 chunks
    const int bb    = bid >> 8;
    const int o     = (bid >> 2) & 63;    // block-uniform
    const int patch = ((bid & 3) << 8) + tid;   // 0..1023
    const int r   = o & 3;
    const int qch = o >> 2;

    if (tid < 128) {
        s_wk[tid] = wk[(r << 7) + tid];   // w_k[(r*16+j)*8+m], tid = j*8+m
        s_wv[tid] = wv[(r << 7) + tid];
    } else if (tid < 136) {
        s_wq[tid - 128] = wq[(o << 3) + (tid - 128)];
    }
    __syncthreads();

    const int hh = patch >> 5, ww = patch & 31;
    const int y0 = hh << 1;

    // pe(y,x) = wp0*locx(x) + wp1*locy(y), loc(t) = -1 + 2t/63 ; uk += 2*pe
    const float wp0 = wp[0];
    const float wp1 = wp[1];
    const float step = 2.0f / 63.0f;
    const float lx0 = -1.0f + step * (float)(ww << 1);
    const float lx1 = lx0 + step;
    const float ly0 = -1.0f + step * (float)y0;
    const float ly1 = ly0 + step;
    float pe2[4];
    pe2[0] = 2.0f * (wp0 * lx0 + wp1 * ly0);
    pe2[1] = 2.0f * (wp0 * lx1 + wp1 * ly0);
    pe2[2] = 2.0f * (wp0 * lx0 + wp1 * ly1);
    pe2[3] = 2.0f * (wp0 * lx1 + wp1 * ly1);

    const float2* __restrict__ x2 = (const float2*)x;
    // float2 strides: channel=16384, m=2048, row=32
    const int sp_off = y0 * 32 + ww;

    // ---- k/v channel pixels: x[bb, qch, m, y0..y0+1, 2ww..2ww+1] ----
    float xk[8][4];
    {
        const int basek = ((bb << 4) + qch) * 16384 + sp_off;
        #pragma unroll
        for (int m = 0; m < 8; m++) {
            float2 a = x2[basek + m * 2048];
            float2 b = x2[basek + m * 2048 + 32];
            xk[m][0] = a.x; xk[m][1] = a.y;
            xk[m][2] = b.x; xk[m][3] = b.y;
        }
    }

    // ---- uk/uv[j][p] ----
    float uk[16][4], uv[16][4];
    #pragma unroll
    for (int j = 0; j < 16; j++) {
        float k0 = pe2[0], k1 = pe2[1], k2 = pe2[2], k3 = pe2[3];
        float v0 = 0.f, v1 = 0.f, v2 = 0.f, v3 = 0.f;
        #pragma unroll
        for (int m = 0; m < 8; m++) {
            const float a = s_wk[j * 8 + m];
            const float c = s_wv[j * 8 + m];
            k0 += a * xk[m][0]; k1 += a * xk[m][1];
            k2 += a * xk[m][2]; k3 += a * xk[m][3];
            v0 += c * xk[m][0]; v1 += c * xk[m][1];
            v2 += c * xk[m][2]; v3 += c * xk[m][3];
        }
        uk[j][0] = k0; uk[j][1] = k1; uk[j][2] = k2; uk[j][3] = k3;
        uv[j][0] = v0; uv[j][1] = v1; uv[j][2] = v2; uv[j][3] = v3;
    }

    // ---- loop over the 16 q channels (= output channel i) ----
    float2* __restrict__ out2 = (float2*)out;
    const int baseq0 = (bb << 4) * 16384 + sp_off;            // float2 units
    const int obase0 = ((bb << 4) * 64 + o) * 2048 + sp_off;  // float2 units

    #pragma unroll 1
    for (int i = 0; i < 16; i++) {
        float uq0 = 0.f, uq1 = 0.f, uq2 = 0.f, uq3 = 0.f;
        float rs0 = 0.f, rs1 = 0.f, rs2 = 0.f, rs3 = 0.f;
        const int bq = baseq0 + i * 16384;
        #pragma unroll
        for (int m = 0; m < 8; m++) {
            float2 a = x2[bq + m * 2048];
            float2 b = x2[bq + m * 2048 + 32];
            const float w = s_wq[m];
            uq0 += w * a.x; uq1 += w * a.y; uq2 += w * b.x; uq3 += w * b.y;
            rs0 += a.x;     rs1 += a.y;     rs2 += b.x;     rs3 += b.y;
        }
        // scaling = h^-0.5 = 0.125 ; residual = mean over m = sum/8
        uq0 *= 0.125f; uq1 *= 0.125f; uq2 *= 0.125f; uq3 *= 0.125f;
        rs0 *= 0.125f; rs1 *= 0.125f; rs2 *= 0.125f; rs3 *= 0.125f;

        // att over j, softmax
        float att[16];
        float mx = -1e30f;
        #pragma unroll
        for (int j = 0; j < 16; j++) {
            const float a = uq0 * uk[j][0] + uq1 * uk[j][1]
                          + uq2 * uk[j][2] + uq3 * uk[j][3];
            att[j] = a;
            mx = fmaxf(mx, a);
        }
        float sum = 0.f;
        #pragma unroll
        for (int j = 0; j < 16; j++) {
            const float e = __expf(att[j] - mx);
            att[j] = e;
            sum += e;
        }
        const float rcp = 1.0f / sum;

        float o0 = 0.f, o1 = 0.f, o2 = 0.f, o3 = 0.f;
        #pragma unroll
        for (int j = 0; j < 16; j++) {
            const float a = att[j];
            o0 += a * uv[j][0]; o1 += a * uv[j][1];
            o2 += a * uv[j][2]; o3 += a * uv[j][3];
        }
        o0 = o0 * rcp + rs0; o1 = o1 * rcp + rs1;
        o2 = o2 * rcp + rs2; o3 = o3 * rcp + rs3;

        const int ob = obase0 + i * 131072;     // i stride = 64*64*64/2 float2
        out2[ob]      = make_float2(o0, o1);    // row y0
        out2[ob + 32] = make_float2(o2, o3);    // row y0+1
    }
}

extern "C" void kernel_launch(void* const* d_in, const int* in_sizes, int n_in,
                              void* d_out, int out_size, void* d_ws, size_t ws_size,
                              hipStream_t stream) {
    const float* x  = (const float*)d_in[0];
    const float* wq = (const float*)d_in[1];
    const float* wk = (const float*)d_in[2];
    const float* wv = (const float*)d_in[3];
    const float* wp = (const float*)d_in[4];
    float* out = (float*)d_out;
    // 4 bb * 64 o * 4 patch-chunks = 1024 blocks of 256 threads
    adapt_attn<<<dim3(1024), dim3(256), 0, stream>>>(x, wq, wk, wv, wp, out);
}

// Round 4
// 123.067 us; speedup vs baseline: 1.0034x; 1.0034x over previous
//
#include <hip/hip_runtime.h>

typedef unsigned int u32;
typedef float v2f __attribute__((ext_vector_type(2)));

// ---- problem ----
// x:[4,16,8,64,64] f32, w_q/w_k/w_v:[64,8] f32, w_p:[2] f32
// out:[4,16,64,64,64] f32
// Attention batch B = bb*64 + o (raw-reinterpret trick):
//   q-side: channel i (all 16), conv row o
//   k/v-side: channel o>>2 (fixed), conv rows (o&3)*16 + j, j in [0,16)
//   uk gets +2*pe; scaling 0.125; residual = mean over m of x[bb, i].
// Pixel pairs (y0 row = .x/.y of 'a', y1 row = 'b') -> v_pk_fma_f32.

__global__ __launch_bounds__(256, 1) void adapt_attn(
    const float* __restrict__ x,  const float* __restrict__ wq,
    const float* __restrict__ wk, const float* __restrict__ wv,
    const float* __restrict__ wp, float* __restrict__ out)
{
    __shared__ __align__(16) float s_wk[128];   // w_k rows (o&3)*16..+16, [16][8]
    __shared__ __align__(16) float s_wv[128];
    __shared__ float s_wq[8];                   // w_q row o, pre-scaled by 0.125

    const int tid = threadIdx.x;
    const int bid = blockIdx.x;           // 1024 blocks = 4 bb * 64 o * 4 chunks
    const int bb    = bid >> 8;
    const int o     = (bid >> 2) & 63;    // block-uniform
    const int patch = ((bid & 3) << 8) + tid;   // 0..1023
    const int r   = o & 3;
    const int qch = o >> 2;

    if (tid < 128) {
        s_wk[tid] = wk[(r << 7) + tid];   // tid = j*8+m
        s_wv[tid] = wv[(r << 7) + tid];
    } else if (tid < 136) {
        s_wq[tid - 128] = 0.125f * wq[(o << 3) + (tid - 128)];
    }
    __syncthreads();

    const int hh = patch >> 5, ww = patch & 31;
    const int y0 = hh << 1;

    // pe(y,x) = wp0*locx + wp1*locy, loc(t) = -1 + 2t/63 ; uk += 2*pe
    const float wp0 = wp[0];
    const float wp1 = wp[1];
    const float step = 2.0f / 63.0f;
    const float lx0 = -1.0f + step * (float)(ww << 1);
    const float lx1 = lx0 + step;
    const float ly0 = -1.0f + step * (float)y0;
    const float ly1 = ly0 + step;
    v2f pea = { 2.0f * (wp0 * lx0 + wp1 * ly0), 2.0f * (wp0 * lx1 + wp1 * ly0) };
    v2f peb = { 2.0f * (wp0 * lx0 + wp1 * ly1), 2.0f * (wp0 * lx1 + wp1 * ly1) };

    const v2f* __restrict__ x2 = (const v2f*)x;
    // v2f strides: channel=16384, m=2048, row=32
    const int sp_off = y0 * 32 + ww;

    // ---- k/v channel pixels ----
    v2f xa[8], xb[8];
    {
        const int basek = ((bb << 4) + qch) * 16384 + sp_off;
        #pragma unroll
        for (int m = 0; m < 8; m++) {
            xa[m] = x2[basek + m * 2048];
            xb[m] = x2[basek + m * 2048 + 32];
        }
    }

    // ---- uk/uv[j] as pixel-pair vectors ----
    v2f uka[16], ukb[16], uva[16], uvb[16];
    const float4* wk4 = (const float4*)s_wk;
    const float4* wv4 = (const float4*)s_wv;
    #pragma unroll
    for (int j = 0; j < 16; j++) {
        const float4 w0 = wk4[j * 2], w1 = wk4[j * 2 + 1];
        const float4 c0 = wv4[j * 2], c1 = wv4[j * 2 + 1];
        v2f ka = pea, kb = peb;
        v2f va = {0.f, 0.f}, vb = {0.f, 0.f};
        ka += xa[0] * w0.x; kb += xb[0] * w0.x; va += xa[0] * c0.x; vb += xb[0] * c0.x;
        ka += xa[1] * w0.y; kb += xb[1] * w0.y; va += xa[1] * c0.y; vb += xb[1] * c0.y;
        ka += xa[2] * w0.z; kb += xb[2] * w0.z; va += xa[2] * c0.z; vb += xb[2] * c0.z;
        ka += xa[3] * w0.w; kb += xb[3] * w0.w; va += xa[3] * c0.w; vb += xb[3] * c0.w;
        ka += xa[4] * w1.x; kb += xb[4] * w1.x; va += xa[4] * c1.x; vb += xb[4] * c1.x;
        ka += xa[5] * w1.y; kb += xb[5] * w1.y; va += xa[5] * c1.y; vb += xb[5] * c1.y;
        ka += xa[6] * w1.z; kb += xb[6] * w1.z; va += xa[6] * c1.z; vb += xb[6] * c1.z;
        ka += xa[7] * w1.w; kb += xb[7] * w1.w; va += xa[7] * c1.w; vb += xb[7] * c1.w;
        uka[j] = ka; ukb[j] = kb; uva[j] = va; uvb[j] = vb;
    }

    // w_q row in registers (8 broadcast LDS reads, once)
    float wqr[8];
    #pragma unroll
    for (int m = 0; m < 8; m++) wqr[m] = s_wq[m];

    // ---- loop over the 16 q channels (= output channel i) ----
    v2f* __restrict__ out2 = (v2f*)out;
    const int baseq0 = (bb << 4) * 16384 + sp_off;            // v2f units
    const int obase0 = ((bb << 4) * 64 + o) * 2048 + sp_off;  // v2f units

    #pragma unroll 1
    for (int i = 0; i < 16; i++) {
        const int bq = baseq0 + i * 16384;
        v2f qa[8], qb[8];
        #pragma unroll
        for (int m = 0; m < 8; m++) {
            qa[m] = x2[bq + m * 2048];
            qb[m] = x2[bq + m * 2048 + 32];
        }
        v2f uqa = {0.f, 0.f}, uqb = {0.f, 0.f};
        v2f rsa = {0.f, 0.f}, rsb = {0.f, 0.f};
        #pragma unroll
        for (int m = 0; m < 8; m++) {
            uqa += qa[m] * wqr[m];   // wqr pre-scaled by 0.125
            uqb += qb[m] * wqr[m];
            rsa += qa[m];
            rsb += qb[m];
        }

        // att + softmax (no max-subtract: |att| << 1, overflow impossible)
        float att[16];
        float sum = 0.f;
        #pragma unroll
        for (int j = 0; j < 16; j++) {
            v2f t = uqa * uka[j];
            t += uqb * ukb[j];
            const float e = __expf(t.x + t.y);
            att[j] = e;
            sum += e;
        }
        const float rcp = 1.0f / sum;

        v2f oa = {0.f, 0.f}, ob = {0.f, 0.f};
        #pragma unroll
        for (int j = 0; j < 16; j++) {
            oa += uva[j] * att[j];
            ob += uvb[j] * att[j];
        }
        oa = oa * rcp + rsa * 0.125f;   // residual = mean over m
        ob = ob * rcp + rsb * 0.125f;

        const int obi = obase0 + i * 131072;   // i stride = 64*64*64/2 v2f
        out2[obi]      = oa;    // row y0
        out2[obi + 32] = ob;    // row y0+1
    }
}

extern "C" void kernel_launch(void* const* d_in, const int* in_sizes, int n_in,
                              void* d_out, int out_size, void* d_ws, size_t ws_size,
                              hipStream_t stream) {
    const float* x  = (const float*)d_in[0];
    const float* wq = (const float*)d_in[1];
    const float* wk = (const float*)d_in[2];
    const float* wv = (const float*)d_in[3];
    const float* wp = (const float*)d_in[4];
    float* out = (float*)d_out;
    adapt_attn<<<dim3(1024), dim3(256), 0, stream>>>(x, wq, wk, wv, wp, out);
}